// Round 3
// baseline (223.675 us; speedup 1.0000x reference)
//
#include <hip/hip_runtime.h>

// Block-diagonal equivariant linear: 256x0e + 256x1o + 128x2e, B=32768, DIM=1664.
// Persistent-block bf16 MFMA:
//  - prep_w: fp32 W -> scaled bf16 in MFMA B-fragment order in d_ws (L2-hot)
//  - linear_main: 512 persistent blocks (8 waves). Weights loaded to VGPRs once
//    per block; grid-stride over batch tiles. Contiguous f32x4 staging loads,
//    deinterleave on LDS write, MFMA from LDS+regs only, LDS-transpose epilogue
//    for D>1 so all global stores are contiguous f32x4.

typedef short short8 __attribute__((ext_vector_type(8)));
typedef short short4v __attribute__((ext_vector_type(4)));
typedef float f32x4 __attribute__((ext_vector_type(4)));

#define DIMF 1664

__device__ __forceinline__ unsigned short f2bf(float f) {
  // round-to-nearest-even fp32 -> bf16 (finite gaussian inputs; no NaN path)
  unsigned int u = __float_as_uint(f);
  u += 0x7fffu + ((u >> 16) & 1u);
  return (unsigned short)(u >> 16);
}

// ws layout per segment: W[u][w] row-major; contraction over u (k), output col w (n).
// Fragment order: element ((ntg*NKS + ks)*64 + lane)*8 + j holds
//   W[k = ks*32 + (lane>>4)*8 + j][n = ntg*16 + (lane&15)] * scale  as bf16.
__global__ __launch_bounds__(256) void prep_w(const float* __restrict__ ws,
                                              unsigned short* __restrict__ wf) {
  int t = blockIdx.x * blockDim.x + threadIdx.x;  // group index, 8 bf16 per group
  int MUL, woff, goff;
  float scale;
  if (t < 8192) {
    MUL = 256; woff = 0; goff = 0; scale = 0.0625f;
  } else if (t < 16384) {
    MUL = 256; woff = 65536; goff = 8192; scale = 0.0625f;
  } else if (t < 18432) {
    MUL = 128; woff = 131072; goff = 16384; scale = 0.088388347648318447f;  // 1/sqrt(128)
  } else {
    return;
  }
  int g = t - goff;
  int l = g & 63;
  int nks = MUL >> 5;
  int ks = (g >> 6) % nks;
  int nt = g / (64 * nks);
  int n = nt * 16 + (l & 15);
  int kb = ks * 32 + (l >> 4) * 8;
  short8 v;
#pragma unroll
  for (int j = 0; j < 8; ++j)
    v[j] = (short)f2bf(ws[woff + (size_t)(kb + j) * MUL + n] * scale);
  *reinterpret_cast<short8*>(wf + (size_t)t * 8) = v;
}

// Stage LDS: A[row = b*D+i][u], u16, row stride LDA = MUL+8
//   -> b128 A-frag reads verified conflict-free (row byte stride 528/272 = 16*odd).
// Epi LDS: E[m][w], f32, row stride LDN with LDN % 8 == 2
//   -> 4-row lane-groups land at bank offsets {0,8,16,24}: uniform 2-way (free).
template <int MUL, int D, int BMB, bool BIAS>
__device__ __forceinline__ void seg_run(const float* __restrict__ x,
                                        const unsigned short* __restrict__ wf,
                                        const float* __restrict__ bs,
                                        float* __restrict__ out, int t0, int NT,
                                        int nblk, int s, char* lds) {
  constexpr int LDA = MUL + 8;          // u16 units
  constexpr int LDN = MUL + 2;          // f32 units (258 / 130: %8 == 2)
  constexpr int MT = BMB * D;           // A rows (32 / 48 / 80)
  constexpr int NMT = MT / 16;          // m-tiles (2 / 3 / 5)
  constexpr int NTW = MUL / 128;        // n-tiles per wave, 8 waves (2 / 2 / 1)
  constexpr int NKS = MUL / 32;         // k-steps (8 / 8 / 4)
  constexpr int NFR = NTW * NKS;        // weight frags per wave (16 / 16 / 4)
  constexpr int CPR = MUL * D / 4;      // f32x4 per batch row (64 / 192 / 160)
  constexpr int NG = BMB * CPR / 512;   // f32x4 per thread per tile (4 / 6 / 5)

  unsigned short* A = (unsigned short*)lds;
  float* E = (float*)(lds + MT * LDA * 2);

  const int tid = threadIdx.x;
  const int lane = tid & 63;
  const int wave = tid >> 6;
  const int l15 = lane & 15;
  const int lhi = lane >> 4;

  // ---- load this wave's weight fragments once (L2) ----
  short8 wfr[NFR];
#pragma unroll
  for (int nt = 0; nt < NTW; ++nt)
#pragma unroll
    for (int ks = 0; ks < NKS; ++ks) {
      int ntg = wave * NTW + nt;
      wfr[nt * NKS + ks] = *reinterpret_cast<const short8*>(
          wf + ((size_t)(ntg * NKS + ks) * 64 + lane) * 8);
    }

  for (int t = t0; t < NT; t += nblk) {
    const int b0 = t * BMB;
    // ---- stage: contiguous f32x4 loads, deinterleave on LDS write ----
#pragma unroll
    for (int it = 0; it < NG; ++it) {
      int g = tid + it * 512;
      int r = g / CPR;
      int c4 = g - r * CPR;
      f32x4 v = *reinterpret_cast<const f32x4*>(x + (size_t)(b0 + r) * DIMF + s + c4 * 4);
      if (D == 1) {
        short4v p;
#pragma unroll
        for (int j = 0; j < 4; ++j) p[j] = (short)f2bf(v[j]);
        *reinterpret_cast<short4v*>(&A[r * LDA + c4 * 4]) = p;
      } else {
#pragma unroll
        for (int j = 0; j < 4; ++j) {
          int col = c4 * 4 + j;
          int u = col / D;
          int i = col - u * D;
          A[(r * D + i) * LDA + u] = f2bf(v[j]);
        }
      }
    }
    __syncthreads();  // B1: stage visible (also fences prev-iter epi reads)

    // ---- MFMA: LDS + registers only ----
    f32x4 acc[NMT][NTW];
#pragma unroll
    for (int a = 0; a < NMT; ++a)
#pragma unroll
      for (int b = 0; b < NTW; ++b) acc[a][b] = (f32x4){0.f, 0.f, 0.f, 0.f};
#pragma unroll
    for (int ks = 0; ks < NKS; ++ks) {
      short8 af[NMT];
#pragma unroll
      for (int mt = 0; mt < NMT; ++mt)
        af[mt] = *reinterpret_cast<const short8*>(
            &A[(mt * 16 + l15) * LDA + ks * 32 + lhi * 8]);
#pragma unroll
      for (int nt = 0; nt < NTW; ++nt)
#pragma unroll
        for (int mt = 0; mt < NMT; ++mt)
          acc[mt][nt] = __builtin_amdgcn_mfma_f32_16x16x32_bf16(af[mt], wfr[nt * NKS + ks],
                                                                acc[mt][nt], 0, 0, 0);
    }

    if (BIAS) {
      // seg0 (D==1): direct stores, 16-lane groups are 64B-contiguous (dense lines)
#pragma unroll
      for (int nt = 0; nt < NTW; ++nt) {
        int n = (wave * NTW + nt) * 16 + l15;
        float bias = bs[n];
#pragma unroll
        for (int mt = 0; mt < NMT; ++mt)
#pragma unroll
          for (int q = 0; q < 4; ++q) {
            int m = mt * 16 + lhi * 4 + q;
            out[(size_t)(b0 + m) * DIMF + s + n] = acc[mt][nt][q] + bias;
          }
      }
      __syncthreads();  // B2: all A-reads done before next stage
    } else {
      // ---- epilogue transpose: acc -> E[m][w] -> contiguous f32x4 stores ----
#pragma unroll
      for (int nt = 0; nt < NTW; ++nt) {
        int n = (wave * NTW + nt) * 16 + l15;
#pragma unroll
        for (int mt = 0; mt < NMT; ++mt)
#pragma unroll
          for (int q = 0; q < 4; ++q)
            E[(mt * 16 + lhi * 4 + q) * LDN + n] = acc[mt][nt][q];
      }
      __syncthreads();  // B2: epi visible, all A-reads done
#pragma unroll
      for (int it = 0; it < NG; ++it) {
        int g = tid + it * 512;
        int r = g / CPR;
        int c4 = g - r * CPR;
        f32x4 o;
#pragma unroll
        for (int j = 0; j < 4; ++j) {
          int c = c4 * 4 + j;
          int w = c / D;
          int i = c - w * D;
          o[j] = E[(r * D + i) * LDN + w];
        }
        *reinterpret_cast<f32x4*>(out + (size_t)(b0 + r) * DIMF + s + c4 * 4) = o;
      }
      // no barrier here: next iter's B1 fences epi reads vs epi writes
    }
  }
}

__global__ __launch_bounds__(512, 4) void linear_main(const float* __restrict__ x,
                                                      const unsigned short* __restrict__ wf,
                                                      const float* __restrict__ bs,
                                                      float* __restrict__ out) {
  // seg1 worst case: stage 48*264*2 = 25344 B + epi 48*258*4 = 49536 B
  __shared__ __align__(16) char lds[25344 + 49536];
  int blk = blockIdx.x;
  if (blk < 80) {
    seg_run<256, 1, 32, true>(x, wf, bs, out, blk, 1024, 80, 0, lds);
  } else if (blk < 316) {
    seg_run<256, 3, 16, false>(x, wf + 65536, bs, out, blk - 80, 2048, 236, 256, lds);
  } else {
    seg_run<128, 5, 16, false>(x, wf + 131072, bs, out, blk - 316, 2048, 196, 1024, lds);
  }
}

extern "C" void kernel_launch(void* const* d_in, const int* in_sizes, int n_in,
                              void* d_out, int out_size, void* d_ws, size_t ws_size,
                              hipStream_t stream) {
  const float* ws = (const float*)d_in[0];  // 147456
  const float* bs = (const float*)d_in[1];  // 256
  const float* x = (const float*)d_in[2];   // 32768 x 1664
  float* out = (float*)d_out;
  unsigned short* wf = (unsigned short*)d_ws;  // 147456 bf16 = 294912 B

  hipLaunchKernelGGL(prep_w, dim3(72), dim3(256), 0, stream, ws, wf);
  hipLaunchKernelGGL(linear_main, dim3(512), dim3(512), 0, stream, x, wf, bs, out);
}

// Round 4
// 127.767 us; speedup vs baseline: 1.7506x; 1.7506x over previous
//
#include <hip/hip_runtime.h>

// Block-diagonal equivariant linear: 256x0e + 256x1o + 128x2e, B=32768, DIM=1664.
// Round-2 structure (one tile per block, 4 waves, 1 barrier, direct stores) +
// async staging: global_load_lds (width 16) stages x LINEARLY in fp32 (no VGPR
// round-trip -> deep MLP); deinterleave + bf16 convert happen at the LDS->reg
// A-fragment read where VALU/LDS pipes are idle.

typedef short short8 __attribute__((ext_vector_type(8)));
typedef float f32x4 __attribute__((ext_vector_type(4)));

#define DIMF 1664

__device__ __forceinline__ unsigned short f2bf(float f) {
  // round-to-nearest-even fp32 -> bf16 (finite gaussian inputs; no NaN path)
  unsigned int u = __float_as_uint(f);
  u += 0x7fffu + ((u >> 16) & 1u);
  return (unsigned short)(u >> 16);
}

__device__ __forceinline__ void gload16(const float* g, float* l) {
  // 16B global -> LDS direct (dest = wave-uniform base + lane*16)
  __builtin_amdgcn_global_load_lds(
      (const __attribute__((address_space(1))) void*)g,
      (__attribute__((address_space(3))) void*)l, 16, 0, 0);
}

// ws layout per segment: W[u][w] row-major; contraction over u (k), output col w (n).
// Fragment order: element ((ntg*NKS + ks)*64 + lane)*8 + j holds
//   W[k = ks*32 + (lane>>4)*8 + j][n = ntg*16 + (lane&15)] * scale  as bf16.
__global__ __launch_bounds__(256) void prep_w(const float* __restrict__ ws,
                                              unsigned short* __restrict__ wf) {
  int t = blockIdx.x * blockDim.x + threadIdx.x;  // group index, 8 bf16 per group
  int MUL, woff, goff;
  float scale;
  if (t < 8192) {
    MUL = 256; woff = 0; goff = 0; scale = 0.0625f;
  } else if (t < 16384) {
    MUL = 256; woff = 65536; goff = 8192; scale = 0.0625f;
  } else if (t < 18432) {
    MUL = 128; woff = 131072; goff = 16384; scale = 0.088388347648318447f;  // 1/sqrt(128)
  } else {
    return;
  }
  int g = t - goff;
  int l = g & 63;
  int nks = MUL >> 5;
  int ks = (g >> 6) % nks;
  int nt = g / (64 * nks);
  int n = nt * 16 + (l & 15);
  int kb = ks * 32 + (l >> 4) * 8;
  short8 v;
#pragma unroll
  for (int j = 0; j < 8; ++j)
    v[j] = (short)f2bf(ws[woff + (size_t)(kb + j) * MUL + n] * scale);
  *reinterpret_cast<short8*>(wf + (size_t)t * 8) = v;
}

// LDS: x tile staged linearly in fp32, group-of-GR-rows stride GSF f32
// (GSF*4 % 16 == 0 so 1KB gload issues tile each group's data exactly).
//   seg0: GR=1 GSF=260  (stride%32= 4 banks -> b128 reads 2-way, free)
//   seg1: GR=1 GSF=772  (scalar gather reads ~2-4 way, cheap)
//   seg2: GR=2 GSF=1288 (2 rows = exactly 5KB data, pad 32B)
template <int MUL, int D, int BMB, int GR, int GSF, bool BIAS>
__device__ __forceinline__ void seg_run(const float* __restrict__ x,
                                        const unsigned short* __restrict__ wf,
                                        const float* __restrict__ bs,
                                        float* __restrict__ out, int blk, int s,
                                        float* A32) {
  constexpr int SEGW = MUL * D;          // f32 per row (256 / 768 / 640)
  constexpr int ISS = GR * SEGW / 256;   // 1KB issues per group (1 / 3 / 5)
  constexpr int NGRP = BMB / GR;         // groups (32 / 16 / 8)
  constexpr int NISS = NGRP * ISS;       // issues per block (32 / 48 / 40)
  constexpr int MT = BMB * D;            // A rows (32 / 48 / 80)
  constexpr int NMT = MT / 16;           // m-tiles (2 / 3 / 5)
  constexpr int NTW = MUL / 64;          // n-tiles per wave, 4 waves (4 / 4 / 2)
  constexpr int NKS = MUL / 32;          // k-steps (8 / 8 / 4)

  const int tid = threadIdx.x;
  const int lane = tid & 63;
  const int wave = tid >> 6;
  const int l15 = lane & 15;
  const int lhi = lane >> 4;
  const int b0 = blk * BMB;

  // ---- async stage: all issues in flight, no VGPR round-trip ----
  for (int m = wave; m < NISS; m += 4) {
    int g = m / ISS;
    int j = m - g * ISS;
    int q = j * 256 + lane * 4;          // f32 index within group's flat data
    int r = g * GR + q / SEGW;           // batch row (per-lane; may split in-issue)
    int c = q % SEGW;
    gload16(x + (size_t)(b0 + r) * DIMF + s + c, A32 + g * GSF + j * 256);
  }
  asm volatile("s_waitcnt vmcnt(0)" ::: "memory");
  __syncthreads();  // the only barrier in the block

  // ---- per-thread A-row offsets ----
  int rowoff[NMT];
#pragma unroll
  for (int mt = 0; mt < NMT; ++mt) {
    int ar = mt * 16 + l15;
    int b = ar / D;
    int i = ar - b * D;
    rowoff[mt] = (b / GR) * GSF + (b % GR) * SEGW + i;
  }

  // ---- MFMA: LDS reads + convert, B-frags streamed from L2 ----
  f32x4 acc[NMT][NTW];
#pragma unroll
  for (int a = 0; a < NMT; ++a)
#pragma unroll
    for (int b = 0; b < NTW; ++b) acc[a][b] = (f32x4){0.f, 0.f, 0.f, 0.f};

#pragma unroll
  for (int ks = 0; ks < NKS; ++ks) {
    short8 af[NMT];
#pragma unroll
    for (int mt = 0; mt < NMT; ++mt) {
      if (D == 1) {
        f32x4 lo = *reinterpret_cast<const f32x4*>(&A32[rowoff[mt] + ks * 32 + lhi * 8]);
        f32x4 hi =
            *reinterpret_cast<const f32x4*>(&A32[rowoff[mt] + ks * 32 + lhi * 8 + 4]);
#pragma unroll
        for (int j = 0; j < 4; ++j) {
          af[mt][j] = (short)f2bf(lo[j]);
          af[mt][j + 4] = (short)f2bf(hi[j]);
        }
      } else {
#pragma unroll
        for (int j = 0; j < 8; ++j)
          af[mt][j] = (short)f2bf(A32[rowoff[mt] + (ks * 32 + lhi * 8 + j) * D]);
      }
    }
#pragma unroll
    for (int nt = 0; nt < NTW; ++nt) {
      int ntg = wave * NTW + nt;
      short8 bfr = *reinterpret_cast<const short8*>(
          wf + ((size_t)(ntg * NKS + ks) * 64 + lane) * 8);
#pragma unroll
      for (int mt = 0; mt < NMT; ++mt)
        acc[mt][nt] =
            __builtin_amdgcn_mfma_f32_16x16x32_bf16(af[mt], bfr, acc[mt][nt], 0, 0, 0);
    }
  }

  // ---- epilogue: C/D layout col = lane&15, row = (lane>>4)*4 + q ----
#pragma unroll
  for (int nt = 0; nt < NTW; ++nt) {
    int n = wave * (MUL / 4) + nt * 16 + l15;
    float bias = 0.f;
    if (BIAS) bias = bs[n];
#pragma unroll
    for (int mt = 0; mt < NMT; ++mt) {
#pragma unroll
      for (int q = 0; q < 4; ++q) {
        int m = mt * 16 + lhi * 4 + q;
        int b = m / D;
        int i = m - b * D;
        out[(size_t)(b0 + b) * DIMF + s + n * D + i] = acc[mt][nt][q] + bias;
      }
    }
  }
}

__global__ __launch_bounds__(256) void linear_main(const float* __restrict__ x,
                                                   const unsigned short* __restrict__ wf,
                                                   const float* __restrict__ bs,
                                                   float* __restrict__ out) {
  // max over segments: seg1 16 groups * 772 f32 * 4B = 49408 B
  __shared__ __align__(16) float A32[12352];
  int blk = blockIdx.x;
  if (blk < 1024) {
    seg_run<256, 1, 32, 1, 260, true>(x, wf, bs, out, blk, 0, A32);
  } else if (blk < 3072) {
    seg_run<256, 3, 16, 1, 772, false>(x, wf + 65536, bs, out, blk - 1024, 256, A32);
  } else {
    seg_run<128, 5, 16, 2, 1288, false>(x, wf + 131072, bs, out, blk - 3072, 1024, A32);
  }
}

extern "C" void kernel_launch(void* const* d_in, const int* in_sizes, int n_in,
                              void* d_out, int out_size, void* d_ws, size_t ws_size,
                              hipStream_t stream) {
  const float* ws = (const float*)d_in[0];  // 147456
  const float* bs = (const float*)d_in[1];  // 256
  const float* x = (const float*)d_in[2];   // 32768 x 1664
  float* out = (float*)d_out;
  unsigned short* wf = (unsigned short*)d_ws;  // 147456 bf16 = 294912 B

  hipLaunchKernelGGL(prep_w, dim3(72), dim3(256), 0, stream, ws, wf);
  hipLaunchKernelGGL(linear_main, dim3(1024 + 2048 + 2048), dim3(256), 0, stream, x,
                     wf, bs, out);
}